// Round 2
// baseline (218.791 us; speedup 1.0000x reference)
//
#include <hip/hip_runtime.h>

// x: (B=4, C=64, H=512, W=512) fp32 -> 131072 independent rows of 512.
// FIR (5-tap, SAME pad, cross-correlation) then IIR:
//   y[j] = f[j] - (v0*y[j-3] + v1*y[j-2] + v2*y[j-1]), zero initial state.
//
// One thread per row. Row = 512 floats = 16 chunks of 32 floats; each chunk
// is exactly one 128B-aligned HBM line, read as 8 float4 by the owning
// thread (same-line requests merge in flight -> ~1x fetch efficiency).
// Register double-buffer prefetch keeps a line outstanding during compute.
// No LDS, no barriers; fully unrolled so all arrays live in registers.

constexpr int Wd = 512;
constexpr int F4_PER_ROW = Wd / 4;   // 128
constexpr int NCHUNK = 16;

struct State {
    float xm2, xm1;            // x[c0-2], x[c0-1] carried across chunks
    float ym3, ym2, ym1;       // IIR state
    float a0, a1, a2, a3, a4;  // FIR taps
    float v0, v1, v2;          // feedback taps
};

__device__ __forceinline__ void chunk_compute_store(
    float4* __restrict__ yr, int ci, const float4 (&cv)[8],
    float n0, float n1, State& s)
{
    float xv[32];
    #pragma unroll
    for (int i = 0; i < 8; ++i) {
        xv[4*i+0] = cv[i].x; xv[4*i+1] = cv[i].y;
        xv[4*i+2] = cv[i].z; xv[4*i+3] = cv[i].w;
    }
    float yv[32];
    #pragma unroll
    for (int jj = 0; jj < 32; ++jj) {
        const float m2 = (jj >= 2) ? xv[jj-2] : ((jj == 0) ? s.xm2 : s.xm1);
        const float m1 = (jj >= 1) ? xv[jj-1] : s.xm1;
        const float x0 = xv[jj];
        const float p1 = (jj+1 < 32) ? xv[jj+1] : n0;
        const float p2 = (jj+2 < 32) ? xv[jj+2] : ((jj == 30) ? n0 : n1);
        const float f  = s.a0*m2 + s.a1*m1 + s.a2*x0 + s.a3*p1 + s.a4*p2;
        const float t  = s.v0*s.ym3 + s.v1*s.ym2;       // off the critical chain
        const float yy = (f - t) - s.v2*s.ym1;          // chain: 1 fused op/elem
        yv[jj] = yy;
        s.ym3 = s.ym2; s.ym2 = s.ym1; s.ym1 = yy;
    }
    s.xm2 = xv[30]; s.xm1 = xv[31];
    #pragma unroll
    for (int i = 0; i < 8; ++i) {
        float4 o; o.x = yv[4*i+0]; o.y = yv[4*i+1];
                  o.z = yv[4*i+2]; o.w = yv[4*i+3];
        yr[ci*8 + i] = o;
    }
}

__global__ __launch_bounds__(256)
void iir_conv2d_kernel(const float4* __restrict__ x4,
                       const float* __restrict__ w1,   // (C,1,5)
                       const float* __restrict__ w2,   // (C,3)
                       float4* __restrict__ y4,
                       int nrows)
{
    const int row = blockIdx.x * 256 + threadIdx.x;
    if (row >= nrows) return;
    const int c = (row >> 9) & 63;                      // row = ((b*64)+c)*512 + h

    State s;
    s.a0 = w1[c*5+0]; s.a1 = w1[c*5+1]; s.a2 = w1[c*5+2];
    s.a3 = w1[c*5+3]; s.a4 = w1[c*5+4];
    s.v0 = w2[c*3+0]; s.v1 = w2[c*3+1]; s.v2 = w2[c*3+2];
    s.xm2 = 0.f; s.xm1 = 0.f; s.ym3 = 0.f; s.ym2 = 0.f; s.ym1 = 0.f;

    const float4* __restrict__ xr = x4 + (size_t)row * F4_PER_ROW;
    float4* __restrict__ yr       = y4 + (size_t)row * F4_PER_ROW;

    float4 A[8], B[8];
    #pragma unroll
    for (int i = 0; i < 8; ++i) A[i] = xr[i];           // chunk 0

    #pragma unroll
    for (int ci = 0; ci < NCHUNK; ci += 2) {
        // prefetch odd chunk ci+1 (always exists: ci <= 14)
        #pragma unroll
        for (int i = 0; i < 8; ++i) B[i] = xr[(ci+1)*8 + i];
        chunk_compute_store(yr, ci, A, B[0].x, B[0].y, s);

        if (ci + 2 < NCHUNK) {
            // prefetch even chunk ci+2
            #pragma unroll
            for (int i = 0; i < 8; ++i) A[i] = xr[(ci+2)*8 + i];
            chunk_compute_store(yr, ci+1, B, A[0].x, A[0].y, s);
        } else {
            chunk_compute_store(yr, ci+1, B, 0.f, 0.f, s);  // right zero-pad
        }
    }
}

extern "C" void kernel_launch(void* const* d_in, const int* in_sizes, int n_in,
                              void* d_out, int out_size, void* d_ws, size_t ws_size,
                              hipStream_t stream) {
    const float4* x4 = (const float4*)d_in[0];
    const float*  w1 = (const float*)d_in[1];
    const float*  w2 = (const float*)d_in[2];
    float4* y4 = (float4*)d_out;

    const int nrows = out_size / Wd;                    // 131072
    const int blocks = (nrows + 255) / 256;             // 512
    iir_conv2d_kernel<<<blocks, 256, 0, stream>>>(x4, w1, w2, y4, nrows);
}

// Round 3
// 152.110 us; speedup vs baseline: 1.4384x; 1.4384x over previous
//
#include <hip/hip_runtime.h>

// x: (B=4, C=64, H=512, W=512) fp32 -> 131072 independent rows of 512 cols.
// FIR: f[j] = sum_k a[k]*x[j-2+k] (SAME zero-pad), then IIR:
//   y[j] = f[j] - (v0*y[j-3] + v1*y[j-2] + v2*y[j-1]), zero initial state.
//
// Segment-parallel via linearity: thread = (row, 32-col segment).
//   y_p   : particular solution with zero segment-entry state (serial, 32 steps)
//   h_k   : homogeneous response vectors (per channel, 32x3, one thread/block)
//   chain : s_{seg+1} = T*s_seg + p_seg  (T = rows h29,h30,h31), one thread/row
//   fixup : y[k] = y_p[k] + h_k . s_seg
// Global I/O fully coalesced through LDS; tile layout [8][16][9*float4]
// (36-float segment pitch) gives uniform bank-group coverage for all b128 ops.

constexpr int Wd     = 512;
constexpr int TROWS  = 8;     // rows per block
constexpr int NT     = 128;   // threads per block
constexpr int SEGS   = 16;    // segments per row
constexpr int SEGP4  = 9;     // float4 pitch per segment (8 data + 1 pad)
constexpr int ROWP4  = SEGS * SEGP4;  // 144 float4 per row in LDS
constexpr int F4ROW  = Wd / 4;        // 128 data float4 per row

__global__ __launch_bounds__(NT, 4)
void iir_conv2d_kernel(const float4* __restrict__ x4,
                       const float* __restrict__ w1,   // (C,1,5)
                       const float* __restrict__ w2,   // (C,3)
                       float4* __restrict__ y4)
{
    __shared__ float4 tile[TROWS * ROWP4];   // 18432 B, x then y in place
    __shared__ float  ps[TROWS][SEGS][3];    // boundary states (p_seg, then s_seg)
    __shared__ float  Htab[32][3];           // homogeneous responses h_k

    const int tid  = threadIdx.x;
    const int row0 = blockIdx.x * TROWS;     // 8 | 512 -> channel uniform per block
    const int c    = (row0 >> 9) & 63;

    // ---- stage x: issue 8 coalesced 16B loads, then LDS writes ----
    const float4* __restrict__ xb = x4 + (size_t)row0 * F4ROW;
    float4 st[8];
    #pragma unroll
    for (int it = 0; it < 8; ++it) st[it] = xb[it * NT + tid];

    // H table (one thread; ~100 serial VALU ops, hidden under the loads)
    if (tid == 0) {
        const float v0 = w2[c*3+0], v1 = w2[c*3+1], v2 = w2[c*3+2];
        float h3[3] = {1.f, 0.f, 0.f};   // h[k-3]
        float h2[3] = {0.f, 1.f, 0.f};   // h[k-2]
        float h1[3] = {0.f, 0.f, 1.f};   // h[k-1]
        for (int k = 0; k < 32; ++k) {
            #pragma unroll
            for (int j = 0; j < 3; ++j) {
                const float n = -(v0*h3[j] + v1*h2[j] + v2*h1[j]);
                Htab[k][j] = n;
                h3[j] = h2[j]; h2[j] = h1[j]; h1[j] = n;
            }
        }
    }

    #pragma unroll
    for (int it = 0; it < 8; ++it) {
        const int idx = it * NT + tid;
        const int r = idx >> 7, g = idx & 127;
        tile[r * ROWP4 + (g >> 3) * SEGP4 + (g & 7)] = st[it];
    }
    __syncthreads();

    // ---- phase 1: per-segment particular solution ----
    const int r = tid >> 4;        // row within tile
    const int s = tid & 15;        // segment
    const float a0 = w1[c*5+0], a1 = w1[c*5+1], a2 = w1[c*5+2],
                a3 = w1[c*5+3], a4 = w1[c*5+4];
    const float v0 = w2[c*3+0], v1 = w2[c*3+1], v2 = w2[c*3+2];

    float4 xf[10];                 // cols j0-4 .. j0+35 (g = 8s-1 .. 8s+8)
    #pragma unroll
    for (int k = 0; k < 10; ++k) {
        const int g = s * 8 + k - 1;
        const bool valid = (g >= 0) && (g < F4ROW);
        const int gg = valid ? g : 0;
        float4 v = tile[r * ROWP4 + (gg >> 3) * SEGP4 + (gg & 7)];
        if (!valid) { v.x = 0.f; v.y = 0.f; v.z = 0.f; v.w = 0.f; }
        xf[k] = v;
    }
    float xfl[40];
    #pragma unroll
    for (int k = 0; k < 10; ++k) {
        xfl[4*k+0] = xf[k].x; xfl[4*k+1] = xf[k].y;
        xfl[4*k+2] = xf[k].z; xfl[4*k+3] = xf[k].w;
    }
    float y[32];
    {
        float ym3 = 0.f, ym2 = 0.f, ym1 = 0.f;
        #pragma unroll
        for (int k = 0; k < 32; ++k) {
            // col j0+k: x[j-2..j+2] = xfl[k+2 .. k+6]
            const float f = a0*xfl[k+2] + a1*xfl[k+3] + a2*xfl[k+4]
                          + a3*xfl[k+5] + a4*xfl[k+6];
            const float t = v0*ym3 + v1*ym2;          // off the serial chain
            const float yy = (f - t) - v2*ym1;
            y[k] = yy;
            ym3 = ym2; ym2 = ym1; ym1 = yy;
        }
    }
    ps[r][s][0] = y[29]; ps[r][s][1] = y[30]; ps[r][s][2] = y[31];
    __syncthreads();

    // ---- chain: serial over 16 segments, one thread per row ----
    if (tid < TROWS) {
        float s0 = 0.f, s1 = 0.f, s2 = 0.f;
        for (int seg = 0; seg < SEGS; ++seg) {
            const float p0 = ps[tid][seg][0], p1 = ps[tid][seg][1],
                        p2 = ps[tid][seg][2];
            ps[tid][seg][0] = s0; ps[tid][seg][1] = s1; ps[tid][seg][2] = s2;
            const float n0 = p0 + Htab[29][0]*s0 + Htab[29][1]*s1 + Htab[29][2]*s2;
            const float n1 = p1 + Htab[30][0]*s0 + Htab[30][1]*s1 + Htab[30][2]*s2;
            const float n2 = p2 + Htab[31][0]*s0 + Htab[31][1]*s1 + Htab[31][2]*s2;
            s0 = n0; s1 = n1; s2 = n2;
        }
    }
    __syncthreads();

    // ---- phase 3: homogeneous fixup, write y into tile (in place over x) ----
    {
        const float s0 = ps[r][s][0], s1 = ps[r][s][1], s2 = ps[r][s][2];
        #pragma unroll
        for (int k = 0; k < 32; ++k)
            y[k] += Htab[k][0]*s0 + Htab[k][1]*s1 + Htab[k][2]*s2;
    }
    #pragma unroll
    for (int u = 0; u < 8; ++u) {
        float4 o;
        o.x = y[4*u+0]; o.y = y[4*u+1]; o.z = y[4*u+2]; o.w = y[4*u+3];
        tile[r * ROWP4 + s * SEGP4 + u] = o;
    }
    __syncthreads();

    // ---- drain: coalesced stores ----
    float4* __restrict__ yb = y4 + (size_t)row0 * F4ROW;
    #pragma unroll
    for (int it = 0; it < 8; ++it) {
        const int idx = it * NT + tid;
        const int rr = idx >> 7, g = idx & 127;
        yb[idx] = tile[rr * ROWP4 + (g >> 3) * SEGP4 + (g & 7)];
    }
}

extern "C" void kernel_launch(void* const* d_in, const int* in_sizes, int n_in,
                              void* d_out, int out_size, void* d_ws, size_t ws_size,
                              hipStream_t stream) {
    const float4* x4 = (const float4*)d_in[0];
    const float*  w1 = (const float*)d_in[1];
    const float*  w2 = (const float*)d_in[2];
    float4* y4 = (float4*)d_out;

    const int nrows  = out_size / Wd;        // 131072
    const int blocks = nrows / TROWS;        // 16384
    iir_conv2d_kernel<<<blocks, NT, 0, stream>>>(x4, w1, w2, y4);
}